// Round 3
// baseline (1194.419 us; speedup 1.0000x reference)
//
#include <hip/hip_runtime.h>
#include <hip/hip_bf16.h>
#include <math.h>

// ---- problem constants ----
#define B_    4
#define S_    2048
#define D_    768
#define H_    8
#define HD_   96
#define EXPD_ 3072
#define MSZ   8192   // B*S
#define CH_   2048   // FFN M-chunk

typedef __bf16 bf16;
typedef __bf16 bf16x8 __attribute__((ext_vector_type(8)));
typedef float  f32x4  __attribute__((ext_vector_type(4)));

// MFMA 16x16x32 bf16 lane layouts (HW-verified per guide):
//   A: A[m = lane&15][k = (lane>>4)*8 + j]   (8 bf16 / lane)
//   B: B[k = (lane>>4)*8 + j][n = lane&15]
//   C/D: C[row = (lane>>4)*4 + r][col = lane&15]  (4 f32 / lane)

__device__ __forceinline__ float gelu_f(float x) {
    float x3 = x * x * x;
    return 0.5f * x * (1.0f + tanhf(0.7978845608028654f * (x + 0.044715f * x3)));
}

// Runtime dtype sniff: if `p` is really a float32 buffer, even bf16 indices are
// f32 low-mantissa halves -> random exponents -> some |v|>1e3 / NaN among 64
// samples with certainty. A real bf16 weight tensor (|v| <= ~0.15) never trips.
__device__ __forceinline__ bool sniff_f32(const void* p) {
    const bf16* pb = (const bf16*)p;
    float v = (float)pb[2 * (threadIdx.x & 63)];
    bool big = !(fabsf(v) < 1000.0f);   // true for NaN too
    return __any(big) != 0;
}

__device__ __forceinline__ bf16x8 load8_dyn(const void* base, size_t idx, bool f32in) {
    if (!f32in) {
        return *(const bf16x8*)((const bf16*)base + idx);
    } else {
        f32x4 a = *(const f32x4*)((const float*)base + idx);
        f32x4 b = *(const f32x4*)((const float*)base + idx + 4);
        bf16x8 r;
#pragma unroll
        for (int e = 0; e < 4; ++e) { r[e] = (bf16)a[e]; r[e + 4] = (bf16)b[e]; }
        return r;
    }
}

#define MODE_QKV  0   // out bf16 scattered to [B][H][S][HD]
#define MODE_RES  1   // out bf16 = c + bias + res[m][n]
#define MODE_GELU 2   // out bf16 = gelu(c + bias)

// C = A(MxK) @ Bw(KxN) + bias, tile 128x64, 4 waves, BK=32.
// ADYN/RESDYN: operand comes from d_in (dtype sniffed); otherwise ws bf16.
template<int MODE, bool ADYN, bool RESDYN>
__global__ __launch_bounds__(256) void gemm_kernel(
    const void* __restrict__ A, const void* __restrict__ Bw,
    const void* __restrict__ bias, const void* __restrict__ res,
    bf16* __restrict__ out, int M, int N, int K)
{
    __shared__ __align__(16) bf16 Alds[128][40];  // +8 pad
    __shared__ __align__(16) bf16 Bt[64][40];     // B tile transposed: Bt[n][k]

    const bool f32in = sniff_f32(Bw);   // Bw is always a d_in weight

    const int tid  = threadIdx.x;
    const int w    = tid >> 6;
    const int lane = tid & 63;
    const int quad = lane >> 4;
    const int l16  = lane & 15;
    const int m0   = blockIdx.x * 128;
    const int n0   = blockIdx.y * 64;

    f32x4 acc[2][4];
#pragma unroll
    for (int s = 0; s < 2; ++s)
#pragma unroll
        for (int c = 0; c < 4; ++c) acc[s][c] = (f32x4){0.f, 0.f, 0.f, 0.f};

    for (int k0 = 0; k0 < K; k0 += 32) {
        __syncthreads();
        // stage A tile 128x32
#pragma unroll
        for (int v = 0; v < 2; ++v) {
            int i   = tid + v * 256;
            int row = i >> 2;
            int c8  = (i & 3) * 8;
            size_t idx = (size_t)(m0 + row) * K + k0 + c8;
            bf16x8 val = ADYN ? load8_dyn(A, idx, f32in)
                              : *(const bf16x8*)((const bf16*)A + idx);
            *(bf16x8*)(&Alds[row][c8]) = val;
        }
        // stage B tile 32x64, transposed into Bt[n][k]
        {
            int k  = tid >> 3;
            int n8 = (tid & 7) * 8;
            bf16x8 val = load8_dyn(Bw, (size_t)(k0 + k) * N + n0 + n8, f32in);
#pragma unroll
            for (int e = 0; e < 8; ++e) Bt[n8 + e][k] = val[e];
        }
        __syncthreads();

        bf16x8 af0 = *(const bf16x8*)(&Alds[w * 32 + l16][quad * 8]);
        bf16x8 af1 = *(const bf16x8*)(&Alds[w * 32 + 16 + l16][quad * 8]);
#pragma unroll
        for (int c = 0; c < 4; ++c) {
            bf16x8 bfr = *(const bf16x8*)(&Bt[c * 16 + l16][quad * 8]);
            acc[0][c] = __builtin_amdgcn_mfma_f32_16x16x32_bf16(af0, bfr, acc[0][c], 0, 0, 0);
            acc[1][c] = __builtin_amdgcn_mfma_f32_16x16x32_bf16(af1, bfr, acc[1][c], 0, 0, 0);
        }
    }

    // epilogue
#pragma unroll
    for (int s = 0; s < 2; ++s)
#pragma unroll
        for (int c = 0; c < 4; ++c)
#pragma unroll
            for (int r = 0; r < 4; ++r) {
                int m = m0 + w * 32 + s * 16 + quad * 4 + r;
                int n = n0 + c * 16 + l16;
                float bval = f32in ? ((const float*)bias)[n] : (float)((const bf16*)bias)[n];
                float v = acc[s][c][r] + bval;
                if constexpr (MODE == MODE_QKV) {
                    int b  = m >> 11;
                    int ss = m & (S_ - 1);
                    int h  = n / HD_;
                    int hd = n - h * HD_;
                    out[(((size_t)(b * H_ + h)) * S_ + ss) * HD_ + hd] = (bf16)v;
                } else if constexpr (MODE == MODE_RES) {
                    size_t ri = (size_t)m * N + n;
                    float rv = (RESDYN && f32in) ? ((const float*)res)[ri]
                                                 : (float)((const bf16*)res)[ri];
                    out[(size_t)m * N + n] = (bf16)(v + rv);
                } else { // MODE_GELU
                    out[(size_t)m * N + n] = (bf16)gelu_f(v);
                }
            }
}

// Flash attention: grid (S/64, B*H), 256 threads; wave w owns 16 Q rows.
// Q/K/V ws bf16 in [B*H][S][HD]; output ctx bf16 in [B][S][H*HD].
__global__ __launch_bounds__(256) void flash_kernel(
    const bf16* __restrict__ Q, const bf16* __restrict__ Kk,
    const bf16* __restrict__ V, bf16* __restrict__ ctx)
{
    __shared__ __align__(16) bf16 Klds[32][104];
    __shared__ __align__(16) bf16 Vt[96][40];      // Vt[hd][kv]
    __shared__ __align__(16) bf16 Plds[4][16][40]; // per-wave P (16 q x 32 kv)

    const int tid  = threadIdx.x;
    const int w    = tid >> 6;
    const int lane = tid & 63;
    const int quad = lane >> 4;
    const int l16  = lane & 15;
    const int bh   = blockIdx.y;
    const size_t base = (size_t)bh * S_ * HD_;
    const int q0   = blockIdx.x * 64 + w * 16;

    bf16x8 qf[3];
#pragma unroll
    for (int ch = 0; ch < 3; ++ch)
        qf[ch] = *(const bf16x8*)(Q + base + (size_t)(q0 + l16) * HD_ + ch * 32 + quad * 8);

    f32x4 oacc[6];
#pragma unroll
    for (int c = 0; c < 6; ++c) oacc[c] = (f32x4){0.f, 0.f, 0.f, 0.f};
    float m_i[4], l_i[4];
#pragma unroll
    for (int r = 0; r < 4; ++r) { m_i[r] = -1e30f; l_i[r] = 0.f; }

    const float scale = 0.10206207261596577f; // 96^-0.5

    for (int kv0 = 0; kv0 < S_; kv0 += 32) {
        __syncthreads();
        for (int i = tid; i < 384; i += 256) {
            int r  = i / 12;
            int c8 = (i % 12) * 8;
            bf16x8 kv = *(const bf16x8*)(Kk + base + (size_t)(kv0 + r) * HD_ + c8);
            *(bf16x8*)(&Klds[r][c8]) = kv;
            bf16x8 vv = *(const bf16x8*)(V + base + (size_t)(kv0 + r) * HD_ + c8);
#pragma unroll
            for (int e = 0; e < 8; ++e) Vt[c8 + e][r] = vv[e];
        }
        __syncthreads();

        f32x4 sacc[2];
#pragma unroll
        for (int t = 0; t < 2; ++t) {
            sacc[t] = (f32x4){0.f, 0.f, 0.f, 0.f};
#pragma unroll
            for (int ch = 0; ch < 3; ++ch) {
                bf16x8 kf = *(const bf16x8*)(&Klds[t * 16 + l16][ch * 32 + quad * 8]);
                sacc[t] = __builtin_amdgcn_mfma_f32_16x16x32_bf16(qf[ch], kf, sacc[t], 0, 0, 0);
            }
        }

        float alpha[4];
#pragma unroll
        for (int r = 0; r < 4; ++r) {
            float s0 = sacc[0][r] * scale;
            float s1 = sacc[1][r] * scale;
            float mx = fmaxf(s0, s1);
#pragma unroll
            for (int off = 1; off < 16; off <<= 1) mx = fmaxf(mx, __shfl_xor(mx, off));
            float mN = fmaxf(m_i[r], mx);
            alpha[r] = __expf(m_i[r] - mN);
            float p0 = __expf(s0 - mN);
            float p1 = __expf(s1 - mN);
            float rs = p0 + p1;
#pragma unroll
            for (int off = 1; off < 16; off <<= 1) rs += __shfl_xor(rs, off);
            l_i[r] = l_i[r] * alpha[r] + rs;
            m_i[r] = mN;
            Plds[w][quad * 4 + r][l16]      = (bf16)p0;
            Plds[w][quad * 4 + r][16 + l16] = (bf16)p1;
        }
        __syncthreads();  // D-layout -> A-layout via LDS

        bf16x8 pf = *(const bf16x8*)(&Plds[w][l16][quad * 8]);
#pragma unroll
        for (int c = 0; c < 6; ++c) {
#pragma unroll
            for (int r = 0; r < 4; ++r) oacc[c][r] *= alpha[r];
            bf16x8 vf = *(const bf16x8*)(&Vt[c * 16 + l16][quad * 8]);
            oacc[c] = __builtin_amdgcn_mfma_f32_16x16x32_bf16(pf, vf, oacc[c], 0, 0, 0);
        }
    }

    const int b = bh >> 3, h = bh & 7;
#pragma unroll
    for (int r = 0; r < 4; ++r) {
        float inv = 1.0f / l_i[r];
        int srow = q0 + quad * 4 + r;
        size_t rowbase = ((size_t)b * S_ + srow) * D_ + h * HD_;
#pragma unroll
        for (int c = 0; c < 6; ++c)
            ctx[rowbase + c * 16 + l16] = (bf16)(oacc[c][r] * inv);
    }
}

// LayerNorm over D=768, one block per row; input always ws bf16.
// g/be from d_in (dtype sniffed via `sniff`); OUTDYN: out follows input dtype.
template<bool OUTDYN>
__global__ __launch_bounds__(256) void ln_kernel(
    const bf16* __restrict__ in, const void* __restrict__ g, const void* __restrict__ be,
    void* __restrict__ out, const void* __restrict__ sniff)
{
    const bool f32in = sniff_f32(sniff);
    const int row = blockIdx.x, tid = threadIdx.x;
    const int w = tid >> 6, lane = tid & 63;
    __shared__ float red1[4], red2[4];
    const bf16* rp = in + (size_t)row * D_;
    float v0 = (float)rp[tid], v1 = (float)rp[tid + 256], v2 = (float)rp[tid + 512];
    float sum = v0 + v1 + v2;
#pragma unroll
    for (int off = 1; off < 64; off <<= 1) sum += __shfl_xor(sum, off);
    if (lane == 0) red1[w] = sum;
    __syncthreads();
    float mu = (red1[0] + red1[1] + red1[2] + red1[3]) * (1.0f / D_);
    float d0 = v0 - mu, d1 = v1 - mu, d2 = v2 - mu;
    float sq = d0 * d0 + d1 * d1 + d2 * d2;
#pragma unroll
    for (int off = 1; off < 64; off <<= 1) sq += __shfl_xor(sq, off);
    if (lane == 0) red2[w] = sq;
    __syncthreads();
    float var  = (red2[0] + red2[1] + red2[2] + red2[3]) * (1.0f / D_);
    float rstd = rsqrtf(var + 1e-5f);
    float dv[3] = {d0, d1, d2};
#pragma unroll
    for (int j = 0; j < 3; ++j) {
        int c = tid + j * 256;
        float gv = f32in ? ((const float*)g)[c]  : (float)((const bf16*)g)[c];
        float bv = f32in ? ((const float*)be)[c] : (float)((const bf16*)be)[c];
        float y = dv[j] * rstd * gv + bv;
        if (OUTDYN && f32in) ((float*)out)[(size_t)row * D_ + c] = y;
        else                 ((bf16*)out)[(size_t)row * D_ + c] = (bf16)y;
    }
}

extern "C" void kernel_launch(void* const* d_in, const int* in_sizes, int n_in,
                              void* d_out, int out_size, void* d_ws, size_t ws_size,
                              hipStream_t stream)
{
    (void)in_sizes; (void)n_in; (void)out_size; (void)ws_size;
    const void* x   = d_in[0];
    const void* Wq  = d_in[1];
    const void* bq  = d_in[2];
    const void* Wk  = d_in[3];
    const void* bk  = d_in[4];
    const void* Wv  = d_in[5];
    const void* bv  = d_in[6];
    const void* Wo  = d_in[7];
    const void* bo  = d_in[8];
    const void* g1  = d_in[9];
    const void* be1 = d_in[10];
    const void* W1  = d_in[11];
    const void* bf1 = d_in[12];
    const void* W2  = d_in[13];
    const void* bf2 = d_in[14];
    const void* g2  = d_in[15];
    const void* be2 = d_in[16];

    // workspace: exactly 4 bf16 [MSZ][D] regions = 50.33 MB.
    // ctx lives in d_out (bf16 scratch; fully overwritten by final LN).
    const size_t REG = (size_t)MSZ * D_ * 2;
    char* p = (char*)d_ws;
    bf16* Qb  = (bf16*)p;             // later: x1 (LN1 out)
    bf16* Kb  = (bf16*)(p + REG);     // later: h chunk (CH_ x EXPD_ = REG)
    bf16* Vb  = (bf16*)(p + 2 * REG); // later: y2
    bf16* y1b = (bf16*)(p + 3 * REG);
    bf16* ctx = (bf16*)d_out;

    dim3 blk(256);

    // QKV projections -> head-scattered bf16
    gemm_kernel<MODE_QKV, true, false><<<dim3(MSZ / 128, D_ / 64), blk, 0, stream>>>(x, Wq, bq, nullptr, Qb, MSZ, D_, D_);
    gemm_kernel<MODE_QKV, true, false><<<dim3(MSZ / 128, D_ / 64), blk, 0, stream>>>(x, Wk, bk, nullptr, Kb, MSZ, D_, D_);
    gemm_kernel<MODE_QKV, true, false><<<dim3(MSZ / 128, D_ / 64), blk, 0, stream>>>(x, Wv, bv, nullptr, Vb, MSZ, D_, D_);

    // attention -> ctx (in d_out)
    flash_kernel<<<dim3(S_ / 64, B_ * H_), blk, 0, stream>>>(Qb, Kb, Vb, ctx);

    // y1 = ctx@Wo + bo + x
    gemm_kernel<MODE_RES, false, true><<<dim3(MSZ / 128, D_ / 64), blk, 0, stream>>>(ctx, Wo, bo, x, y1b, MSZ, D_, D_);
    // x1 = LN1(y1) -> Qb region (bf16 ws)
    bf16* x1b = Qb;
    ln_kernel<false><<<dim3(MSZ), blk, 0, stream>>>(y1b, g1, be1, x1b, Wq);

    // FFN chunked over M: h chunk in Kb region, y2 in Vb region
    bf16* hb  = Kb;
    bf16* y2b = Vb;
    for (int c0 = 0; c0 < MSZ; c0 += CH_) {
        const bf16* x1c = x1b + (size_t)c0 * D_;
        gemm_kernel<MODE_GELU, false, false><<<dim3(CH_ / 128, EXPD_ / 64), blk, 0, stream>>>(x1c, W1, bf1, nullptr, hb, CH_, EXPD_, D_);
        gemm_kernel<MODE_RES, false, false><<<dim3(CH_ / 128, D_ / 64), blk, 0, stream>>>(hb, W2, bf2, x1c, y2b + (size_t)c0 * D_, CH_, D_, EXPD_);
    }

    // out = LN2(y2) -> d_out (overwrites ctx scratch; dtype follows input)
    ln_kernel<true><<<dim3(MSZ), blk, 0, stream>>>(y2b, g2, be2, d_out, Wq);
}

// Round 4
// 611.776 us; speedup vs baseline: 1.9524x; 1.9524x over previous
//
#include <hip/hip_runtime.h>
#include <hip/hip_bf16.h>
#include <math.h>
#include <stdint.h>

// ---- problem constants ----
#define B_    4
#define S_    2048
#define D_    768
#define H_    8
#define HD_   96
#define EXPD_ 3072
#define MSZ   8192   // B*S

typedef __bf16 bf16;
typedef __bf16 bf16x4 __attribute__((ext_vector_type(4)));
typedef __bf16 bf16x8 __attribute__((ext_vector_type(8)));
typedef float  f32x4  __attribute__((ext_vector_type(4)));

typedef __attribute__((address_space(1))) const uint32_t gu32;
typedef __attribute__((address_space(3))) uint32_t lu32;

__device__ __forceinline__ void async_copy16(const void* g, void* l) {
    __builtin_amdgcn_global_load_lds((gu32*)g, (lu32*)l, 16, 0, 0);
}

__device__ __forceinline__ float gelu_f(float x) {
    float x3 = x * x * x;
    return 0.5f * x * (1.0f + tanhf(0.7978845608028654f * (x + 0.044715f * x3)));
}

// Runtime dtype sniff (see round-2 notes): f32 buffer read as bf16 at even
// indices yields random exponents -> some |v|>=1e3 among 64 samples w.p. ~1.
__device__ __forceinline__ bool sniff_f32(const void* p) {
    const bf16* pb = (const bf16*)p;
    float v = (float)pb[2 * (threadIdx.x & 63)];
    bool big = !(fabsf(v) < 1000.0f);
    return __any(big) != 0;
}

__device__ __forceinline__ float dynld(const void* p, size_t i, bool f32in) {
    return f32in ? ((const float*)p)[i] : (float)((const bf16*)p)[i];
}

#define MODE_QKV  0   // fused QKV: scatter Q,K -> [bh][S][HD]; V -> [bh][HD][S]
#define MODE_RES  1   // out bf16 = c + bias + res
#define MODE_GELU 2   // out bf16 = gelu(c + bias)

// m97-style GEMM: C = A(MxK) @ Bt(NxK)^T + bias. 128x128 tile, BK=32, 4 waves,
// global_load_lds width-16 staging, stride-32 LDS, 16 MFMA/wave/k-step.
template<int MODE, bool ADYN, bool RESDYN>
__global__ __launch_bounds__(256) void gemm2_kernel(
    const void* __restrict__ A, const bf16* __restrict__ Bt,
    const void* __restrict__ b0, const void* __restrict__ b1, const void* __restrict__ b2,
    const void* __restrict__ res, bf16* __restrict__ out,
    int M, int N, int K, const void* __restrict__ sniffp)
{
    __shared__ __align__(16) bf16 As[128 * 32];
    __shared__ __align__(16) bf16 Bs[128 * 32];

    const bool f32in = sniff_f32(sniffp);
    const int tid  = threadIdx.x;
    const int w    = tid >> 6;
    const int lane = tid & 63;
    const int quad = lane >> 4;
    const int l16  = lane & 15;
    const int wr   = w >> 1, wc = w & 1;
    const int m0   = blockIdx.x * 128;
    const int n0   = blockIdx.y * 128;

    const int rA0 = w * 32 + (lane >> 2);   // staged row (a=0); lane-dest = base + lane*16B
    const int cb8 = (lane & 3) * 8;

    f32x4 acc[4][4];
#pragma unroll
    for (int i = 0; i < 4; ++i)
#pragma unroll
        for (int j = 0; j < 4; ++j) acc[i][j] = (f32x4){0.f, 0.f, 0.f, 0.f};

    const bf16*  Abf = (const bf16*)A;
    const float* Af  = (const float*)A;

    for (int k0 = 0; k0 < K; k0 += 32) {
        __syncthreads();
        if (ADYN && f32in) {
#pragma unroll
            for (int a = 0; a < 2; ++a) {
                int row = rA0 + a * 16;
                const float* sp = Af + (size_t)(m0 + row) * K + k0 + cb8;
                f32x4 u0 = *(const f32x4*)sp;
                f32x4 u1 = *(const f32x4*)(sp + 4);
                bf16x8 v;
#pragma unroll
                for (int e = 0; e < 4; ++e) { v[e] = (bf16)u0[e]; v[e + 4] = (bf16)u1[e]; }
                *(bf16x8*)(&As[(size_t)(w * 32 + a * 16) * 32 + lane * 8]) = v;
            }
        } else {
#pragma unroll
            for (int a = 0; a < 2; ++a) {
                int row = rA0 + a * 16;
                async_copy16(Abf + (size_t)(m0 + row) * K + k0 + cb8,
                             &As[(w * 32 + a * 16) * 32]);
            }
        }
#pragma unroll
        for (int a = 0; a < 2; ++a) {
            int row = rA0 + a * 16;
            async_copy16(Bt + (size_t)(n0 + row) * K + k0 + cb8,
                         &Bs[(w * 32 + a * 16) * 32]);
        }
        __syncthreads();

        bf16x8 af[4], bfv[4];
#pragma unroll
        for (int i = 0; i < 4; ++i) {
            af[i]  = *(const bf16x8*)(&As[(wr * 64 + i * 16 + l16) * 32 + quad * 8]);
            bfv[i] = *(const bf16x8*)(&Bs[(wc * 64 + i * 16 + l16) * 32 + quad * 8]);
        }
#pragma unroll
        for (int i = 0; i < 4; ++i)
#pragma unroll
            for (int j = 0; j < 4; ++j)
                acc[i][j] = __builtin_amdgcn_mfma_f32_16x16x32_bf16(af[i], bfv[j], acc[i][j], 0, 0, 0);
    }

    // epilogue
#pragma unroll
    for (int j = 0; j < 4; ++j) {
        int n = n0 + wc * 64 + j * 16 + l16;
        // bias select (wave-uniform per j: 16-consecutive n never crosses a 768-block)
        float bval;
        int which = 0, n2 = n;
        if constexpr (MODE == MODE_QKV) {
            which = n / D_;
            n2 = n - which * D_;
            const void* bp = which == 0 ? b0 : (which == 1 ? b1 : b2);
            bval = dynld(bp, n2, f32in);
        } else {
            bval = dynld(b0, n, f32in);
        }
#pragma unroll
        for (int i = 0; i < 4; ++i) {
#pragma unroll
            for (int r = 0; r < 4; ++r) {
                int m = m0 + wr * 64 + i * 16 + quad * 4 + r;
                float v = acc[i][j][r] + bval;
                if constexpr (MODE == MODE_QKV) {
                    int b  = m >> 11;
                    int ss = m & (S_ - 1);
                    int h  = n2 / HD_;
                    int hd = n2 - h * HD_;
                    int bh = b * H_ + h;
                    size_t dst;
                    if (which < 2)  // Q,K: [bh][S][HD]
                        dst = (size_t)which * (MSZ * D_) + ((size_t)bh * S_ + ss) * HD_ + hd;
                    else            // V transposed: [bh][HD][S]
                        dst = (size_t)2 * (MSZ * D_) + ((size_t)bh * HD_ + hd) * S_ + ss;
                    out[dst] = (bf16)v;
                } else if constexpr (MODE == MODE_RES) {
                    size_t ri = (size_t)m * N + n;
                    float rv = RESDYN ? dynld(res, ri, f32in) : (float)((const bf16*)res)[ri];
                    out[ri] = (bf16)(v + rv);
                } else {
                    out[(size_t)m * N + n] = (bf16)gelu_f(v);
                }
            }
        }
    }
}

// Flash attention, KV-tile 64. Q,K: [bh][S][96]; Vt_g: [bh][96][S] (pre-transposed).
// grid (S/64, B*H), 256 threads; wave w owns 16 Q rows.
__global__ __launch_bounds__(256) void flash_kernel(
    const bf16* __restrict__ Q, const bf16* __restrict__ Kk,
    const bf16* __restrict__ Vt_g, bf16* __restrict__ ctx)
{
    __shared__ __align__(16) bf16 Ks[64][104];    // K tile [kv][hd], padded
    __shared__ __align__(16) bf16 Vs[96][72];     // V^T tile [hd][kv], padded
    __shared__ __align__(16) bf16 Ps[4][16][72];  // per-wave P [q][kv]

    const int tid  = threadIdx.x;
    const int w    = tid >> 6;
    const int lane = tid & 63;
    const int quad = lane >> 4;
    const int l16  = lane & 15;
    const int bh   = blockIdx.y;
    const size_t base = (size_t)bh * S_ * HD_;
    const int q0   = blockIdx.x * 64 + w * 16;

    bf16x8 qf[3];
#pragma unroll
    for (int ch = 0; ch < 3; ++ch)
        qf[ch] = *(const bf16x8*)(Q + base + (size_t)(q0 + l16) * HD_ + ch * 32 + quad * 8);

    f32x4 oacc[6];
#pragma unroll
    for (int c = 0; c < 6; ++c) oacc[c] = (f32x4){0.f, 0.f, 0.f, 0.f};
    float m_i[4], l_i[4];
#pragma unroll
    for (int r = 0; r < 4; ++r) { m_i[r] = -1e30f; l_i[r] = 0.f; }

    const float scale = 0.10206207261596577f; // 96^-0.5

    for (int kv0 = 0; kv0 < S_; kv0 += 64) {
        __syncthreads();
        // stage K tile 64x96 and V^T tile 96x64 (contiguous b128 LDS writes)
#pragma unroll
        for (int jj = 0; jj < 3; ++jj) {
            int i  = tid + jj * 256;
            int r  = i / 12;
            int c8 = (i % 12) * 8;
            *(bf16x8*)(&Ks[r][c8]) =
                *(const bf16x8*)(Kk + base + (size_t)(kv0 + r) * HD_ + c8);
            int hd = i >> 3;
            int cb = (i & 7) * 8;
            *(bf16x8*)(&Vs[hd][cb]) =
                *(const bf16x8*)(Vt_g + base + (size_t)hd * S_ + kv0 + cb);
        }
        __syncthreads();

        // S = Q K^T : four 16x16 kv-tiles
        f32x4 sacc[4];
#pragma unroll
        for (int t = 0; t < 4; ++t) {
            sacc[t] = (f32x4){0.f, 0.f, 0.f, 0.f};
#pragma unroll
            for (int ch = 0; ch < 3; ++ch) {
                bf16x8 kf = *(const bf16x8*)(&Ks[t * 16 + l16][ch * 32 + quad * 8]);
                sacc[t] = __builtin_amdgcn_mfma_f32_16x16x32_bf16(qf[ch], kf, sacc[t], 0, 0, 0);
            }
        }

        // online softmax (row quad*4+r lives in the quad's 16 lanes)
        float alpha[4];
#pragma unroll
        for (int r = 0; r < 4; ++r) {
            float s0 = sacc[0][r] * scale, s1 = sacc[1][r] * scale;
            float s2 = sacc[2][r] * scale, s3 = sacc[3][r] * scale;
            float mx = fmaxf(fmaxf(s0, s1), fmaxf(s2, s3));
#pragma unroll
            for (int off = 1; off < 16; off <<= 1) mx = fmaxf(mx, __shfl_xor(mx, off));
            float mN = fmaxf(m_i[r], mx);
            alpha[r] = __expf(m_i[r] - mN);
            float p0 = __expf(s0 - mN), p1 = __expf(s1 - mN);
            float p2 = __expf(s2 - mN), p3 = __expf(s3 - mN);
            float rs = (p0 + p1) + (p2 + p3);
#pragma unroll
            for (int off = 1; off < 16; off <<= 1) rs += __shfl_xor(rs, off);
            l_i[r] = l_i[r] * alpha[r] + rs;
            m_i[r] = mN;
            int qr = quad * 4 + r;
            Ps[w][qr][l16]      = (bf16)p0;
            Ps[w][qr][16 + l16] = (bf16)p1;
            Ps[w][qr][32 + l16] = (bf16)p2;
            Ps[w][qr][48 + l16] = (bf16)p3;
        }
        __syncthreads();  // D-layout -> A-layout via LDS

        // O = O*alpha + P @ V   (two K=32 halves)
        bf16x8 pf0 = *(const bf16x8*)(&Ps[w][l16][quad * 8]);
        bf16x8 pf1 = *(const bf16x8*)(&Ps[w][l16][32 + quad * 8]);
#pragma unroll
        for (int c = 0; c < 6; ++c) {
#pragma unroll
            for (int r = 0; r < 4; ++r) oacc[c][r] *= alpha[r];
            bf16x8 vf0 = *(const bf16x8*)(&Vs[c * 16 + l16][quad * 8]);
            bf16x8 vf1 = *(const bf16x8*)(&Vs[c * 16 + l16][32 + quad * 8]);
            oacc[c] = __builtin_amdgcn_mfma_f32_16x16x32_bf16(pf0, vf0, oacc[c], 0, 0, 0);
            oacc[c] = __builtin_amdgcn_mfma_f32_16x16x32_bf16(pf1, vf1, oacc[c], 0, 0, 0);
        }
    }

    const int b = bh >> 3, h = bh & 7;
#pragma unroll
    for (int r = 0; r < 4; ++r) {
        float inv = 1.0f / l_i[r];
        int srow = q0 + quad * 4 + r;
        size_t rowbase = ((size_t)b * S_ + srow) * D_ + h * HD_;
#pragma unroll
        for (int c = 0; c < 6; ++c)
            ctx[rowbase + c * 16 + l16] = (bf16)(oacc[c][r] * inv);
    }
}

// LayerNorm over D=768: one wave per row (12 el/lane, bf16x4 vector I/O).
template<bool OUTDYN>
__global__ __launch_bounds__(256) void ln_kernel(
    const bf16* __restrict__ in, const void* __restrict__ g, const void* __restrict__ be,
    void* __restrict__ out, const void* __restrict__ sniffp)
{
    const bool f32in = sniff_f32(sniffp);
    const int w = threadIdx.x >> 6, lane = threadIdx.x & 63;
    const int row = blockIdx.x * 4 + w;
    const size_t rbase = (size_t)row * D_ + lane * 12;

    float v[12];
#pragma unroll
    for (int j = 0; j < 3; ++j) {
        bf16x4 t = *(const bf16x4*)(in + rbase + j * 4);
#pragma unroll
        for (int e = 0; e < 4; ++e) v[j * 4 + e] = (float)t[e];
    }
    float sum = 0.f;
#pragma unroll
    for (int j = 0; j < 12; ++j) sum += v[j];
#pragma unroll
    for (int off = 1; off < 64; off <<= 1) sum += __shfl_xor(sum, off);
    float mu = sum * (1.0f / D_);
    float sq = 0.f;
#pragma unroll
    for (int j = 0; j < 12; ++j) { v[j] -= mu; sq += v[j] * v[j]; }
#pragma unroll
    for (int off = 1; off < 64; off <<= 1) sq += __shfl_xor(sq, off);
    float rstd = rsqrtf(sq * (1.0f / D_) + 1e-5f);

    if (OUTDYN && f32in) {
        float* op = (float*)out + rbase;
#pragma unroll
        for (int j = 0; j < 3; ++j) {
            f32x4 t;
#pragma unroll
            for (int e = 0; e < 4; ++e) {
                int c = lane * 12 + j * 4 + e;
                t[e] = v[j * 4 + e] * rstd * dynld(g, c, true) + dynld(be, c, true);
            }
            *(f32x4*)(op + j * 4) = t;
        }
    } else {
        bf16* op = (bf16*)out + rbase;
#pragma unroll
        for (int j = 0; j < 3; ++j) {
            bf16x4 t;
#pragma unroll
            for (int e = 0; e < 4; ++e) {
                int c = lane * 12 + j * 4 + e;
                t[e] = (bf16)(v[j * 4 + e] * rstd * dynld(g, c, f32in) + dynld(be, c, f32in));
            }
            *(bf16x4*)(op + j * 4) = t;
        }
    }
}

// Transpose src [R][C] (dyn dtype) -> dst [C][R] bf16. 64x64 tiles.
__global__ __launch_bounds__(256) void transpose_kernel(
    const void* __restrict__ src, bf16* __restrict__ dst, int R, int C)
{
    __shared__ bf16 t[64][65];
    const bool f32in = sniff_f32(src);
    const int c0 = blockIdx.x * 64, r0 = blockIdx.y * 64;
    const int tx = threadIdx.x & 63, ty = threadIdx.x >> 6;
#pragma unroll
    for (int i = 0; i < 16; ++i) {
        int rr = ty + i * 4;
        t[rr][tx] = (bf16)dynld(src, (size_t)(r0 + rr) * C + c0 + tx, f32in);
    }
    __syncthreads();
#pragma unroll
    for (int i = 0; i < 16; ++i) {
        int cc = ty + i * 4;
        dst[(size_t)(c0 + cc) * R + r0 + tx] = t[tx][cc];
    }
}

extern "C" void kernel_launch(void* const* d_in, const int* in_sizes, int n_in,
                              void* d_out, int out_size, void* d_ws, size_t ws_size,
                              hipStream_t stream)
{
    (void)in_sizes; (void)n_in; (void)out_size;
    const void* x   = d_in[0];
    const void* Wq  = d_in[1];
    const void* bq  = d_in[2];
    const void* Wk  = d_in[3];
    const void* bk  = d_in[4];
    const void* Wv  = d_in[5];
    const void* bv  = d_in[6];
    const void* Wo  = d_in[7];
    const void* bo  = d_in[8];
    const void* g1  = d_in[9];
    const void* be1 = d_in[10];
    const void* W1  = d_in[11];
    const void* bf1 = d_in[12];
    const void* W2  = d_in[13];
    const void* bf2 = d_in[14];
    const void* g2  = d_in[15];
    const void* be2 = d_in[16];

    const size_t REG_EL = (size_t)MSZ * D_;  // 6.29 M elements
    const size_t REG    = REG_EL * 2;        // 12.58 MB
    char* p = (char*)d_ws;
    bf16* R0 = (bf16*)p;             // Q            -> x1
    bf16* R1 = (bf16*)(p + REG);     // K            -> WoT|W1T|W2T
    bf16* R2 = (bf16*)(p + 2 * REG); // V^T          -> h chunk (small path)
    bf16* R3 = (bf16*)(p + 3 * REG); // y1           -> y2
    bf16* R4 = (bf16*)(p + 4 * REG); // h full (big path only)
    const bool bigws = ws_size >= 8 * REG;

    bf16* qkvT = (bf16*)d_out;       // WqT|WkT|WvT (3.54 MB) before flash
    bf16* ctx  = (bf16*)d_out;       // after QKV GEMM

    dim3 blk(256);

    // 1) transpose Wq/Wk/Wv -> qkvT [2304][768]
    transpose_kernel<<<dim3(12, 12), blk, 0, stream>>>(Wq, qkvT, D_, D_);
    transpose_kernel<<<dim3(12, 12), blk, 0, stream>>>(Wk, qkvT + (size_t)D_ * D_, D_, D_);
    transpose_kernel<<<dim3(12, 12), blk, 0, stream>>>(Wv, qkvT + 2 * (size_t)D_ * D_, D_, D_);

    // 2) fused QKV GEMM: [8192 x 2304] -> Q(R0), K(R1), V^T(R2)
    gemm2_kernel<MODE_QKV, true, false><<<dim3(MSZ / 128, 2304 / 128), blk, 0, stream>>>(
        x, qkvT, bq, bk, bv, nullptr, R0, MSZ, 2304, D_, Wq);

    // 3) flash attention -> ctx (d_out; qkvT dead)
    flash_kernel<<<dim3(S_ / 64, B_ * H_), blk, 0, stream>>>(R0, R1, R2, ctx);

    // 4) transpose Wo/W1/W2 into R1 (K dead)
    bf16* WoT = R1;
    bf16* W1T = WoT + (size_t)D_ * D_;
    bf16* W2T = W1T + (size_t)D_ * EXPD_;
    transpose_kernel<<<dim3(12, 12), blk, 0, stream>>>(Wo, WoT, D_, D_);
    transpose_kernel<<<dim3(48, 12), blk, 0, stream>>>(W1, W1T, D_, EXPD_);
    transpose_kernel<<<dim3(12, 48), blk, 0, stream>>>(W2, W2T, EXPD_, D_);

    // 5) y1 = ctx@Wo + bo + x -> R3
    gemm2_kernel<MODE_RES, false, true><<<dim3(MSZ / 128, D_ / 128), blk, 0, stream>>>(
        ctx, WoT, bo, nullptr, nullptr, x, R3, MSZ, D_, D_, Wq);

    // 6) x1 = LN1(y1) -> R0 (Q dead)
    bf16* x1b = R0;
    ln_kernel<false><<<dim3(MSZ / 4), blk, 0, stream>>>(R3, g1, be1, x1b, Wq);

    // 7/8) FFN (y2 -> R3; y1 dead)
    if (bigws) {
        gemm2_kernel<MODE_GELU, false, false><<<dim3(MSZ / 128, EXPD_ / 128), blk, 0, stream>>>(
            x1b, W1T, bf1, nullptr, nullptr, nullptr, R4, MSZ, EXPD_, D_, Wq);
        gemm2_kernel<MODE_RES, false, false><<<dim3(MSZ / 128, D_ / 128), blk, 0, stream>>>(
            R4, W2T, bf2, nullptr, nullptr, x1b, R3, MSZ, D_, EXPD_, Wq);
    } else {
        const int CH = 2048;  // h chunk = 12.58 MB -> R2 (V dead)
        for (int c0 = 0; c0 < MSZ; c0 += CH) {
            const bf16* x1c = x1b + (size_t)c0 * D_;
            gemm2_kernel<MODE_GELU, false, false><<<dim3(CH / 128, EXPD_ / 128), blk, 0, stream>>>(
                x1c, W1T, bf1, nullptr, nullptr, nullptr, R2, CH, EXPD_, D_, Wq);
            gemm2_kernel<MODE_RES, false, false><<<dim3(CH / 128, D_ / 128), blk, 0, stream>>>(
                R2, W2T, bf2, nullptr, nullptr, x1c, R3 + (size_t)c0 * D_, CH, D_, EXPD_, Wq);
        }
    }

    // 9) out = LN2(y2) -> d_out (ctx dead)
    ln_kernel<true><<<dim3(MSZ / 4), blk, 0, stream>>>(R3, g2, be2, d_out, Wq);
}

// Round 5
// 558.866 us; speedup vs baseline: 2.1372x; 1.0947x over previous
//
#include <hip/hip_runtime.h>
#include <hip/hip_bf16.h>
#include <math.h>
#include <stdint.h>

// ---- problem constants ----
#define B_    4
#define S_    2048
#define D_    768
#define H_    8
#define HD_   96
#define EXPD_ 3072
#define MSZ   8192   // B*S

#define QSCALE 0.14724439f   // HD^-0.5 * log2(e), folded into Q at QKV epilogue
#define M0_    12.0f         // fixed softmax exponent offset (scores*QSCALE sigma~0.44)

typedef __bf16 bf16;
typedef __bf16 bf16x4 __attribute__((ext_vector_type(4)));
typedef __bf16 bf16x8 __attribute__((ext_vector_type(8)));
typedef float  f32x4  __attribute__((ext_vector_type(4)));

typedef __attribute__((address_space(1))) const uint32_t gu32;
typedef __attribute__((address_space(3))) uint32_t lu32;

__device__ __forceinline__ void async_copy16(const void* g, void* l) {
    __builtin_amdgcn_global_load_lds((gu32*)g, (lu32*)l, 16, 0, 0);
}

__device__ __forceinline__ float gelu_f(float x) {
    float x3 = x * x * x;
    return 0.5f * x * (1.0f + tanhf(0.7978845608028654f * (x + 0.044715f * x3)));
}

// Runtime dtype sniff: f32 buffer read as bf16 at even indices yields random
// exponents -> some |v|>=1e3 among 64 samples w.p. ~1. bf16 weights never trip.
__device__ __forceinline__ bool sniff_f32(const void* p) {
    const bf16* pb = (const bf16*)p;
    float v = (float)pb[2 * (threadIdx.x & 63)];
    bool big = !(fabsf(v) < 1000.0f);
    return __any(big) != 0;
}

__device__ __forceinline__ float dynld(const void* p, size_t i, bool f32in) {
    return f32in ? ((const float*)p)[i] : (float)((const bf16*)p)[i];
}

#define MODE_QKV  0   // fused QKV: Q(*QSCALE),K -> [bh][S][HD]; V -> [bh][HD][S]
#define MODE_RES  1   // out bf16 = c + bias + res
#define MODE_GELU 2   // out bf16 = gelu(c + bias)

// m97-style GEMM: C = A(MxK) @ Bt(NxK)^T + bias. Tile 128xBN, BK=32, 4 waves,
// global_load_lds width-16 staging, stride-32 LDS. BN=128: wave 64x64 (16 mfma);
// BN=64: wave 64x32 (8 mfma), 2x grid for small-N shapes (occupancy).
template<int MODE, bool ADYN, bool RESDYN, int BN>
__global__ __launch_bounds__(256) void gemm2_kernel(
    const void* __restrict__ A, const bf16* __restrict__ Bt,
    const void* __restrict__ b0, const void* __restrict__ b1, const void* __restrict__ b2,
    const void* __restrict__ res, bf16* __restrict__ out,
    int M, int N, int K, const void* __restrict__ sniffp)
{
    constexpr int WN = BN / 2;    // wave N extent
    constexpr int NJ = WN / 16;   // acc tiles in N
    __shared__ __align__(16) bf16 As[128 * 32];
    __shared__ __align__(16) bf16 Bs[BN * 32];

    const bool f32in = sniff_f32(sniffp);
    const int tid  = threadIdx.x;
    const int w    = tid >> 6;
    const int lane = tid & 63;
    const int quad = lane >> 4;
    const int l16  = lane & 15;
    const int wr   = w >> 1, wc = w & 1;
    const int m0   = blockIdx.x * 128;
    const int n0   = blockIdx.y * BN;

    const int rsub = lane >> 2;          // staged sub-row within 16-row group
    const int cb8  = (lane & 3) * 8;     // staged col (8-elem units)

    f32x4 acc[4][NJ];
#pragma unroll
    for (int i = 0; i < 4; ++i)
#pragma unroll
        for (int j = 0; j < NJ; ++j) acc[i][j] = (f32x4){0.f, 0.f, 0.f, 0.f};

    const bf16*  Abf = (const bf16*)A;
    const float* Af  = (const float*)A;

    for (int k0 = 0; k0 < K; k0 += 32) {
        __syncthreads();
        // A tile 128x32
        if (ADYN && f32in) {
#pragma unroll
            for (int a = 0; a < 2; ++a) {
                int row = w * 32 + a * 16 + rsub;
                const float* sp = Af + (size_t)(m0 + row) * K + k0 + cb8;
                f32x4 u0 = *(const f32x4*)sp;
                f32x4 u1 = *(const f32x4*)(sp + 4);
                bf16x8 v;
#pragma unroll
                for (int e = 0; e < 4; ++e) { v[e] = (bf16)u0[e]; v[e + 4] = (bf16)u1[e]; }
                *(bf16x8*)(&As[(size_t)(w * 32 + a * 16) * 32 + lane * 8]) = v;
            }
        } else {
#pragma unroll
            for (int a = 0; a < 2; ++a) {
                int row = w * 32 + a * 16 + rsub;
                async_copy16(Abf + (size_t)(m0 + row) * K + k0 + cb8,
                             &As[(w * 32 + a * 16) * 32]);
            }
        }
        // B tile BNx32
#pragma unroll
        for (int a = 0; a < BN / 64; ++a) {
            int row = w * (BN / 4) + a * 16 + rsub;
            async_copy16(Bt + (size_t)(n0 + row) * K + k0 + cb8,
                         &Bs[(w * (BN / 4) + a * 16) * 32]);
        }
        __syncthreads();

        bf16x8 af[4], bfv[NJ];
#pragma unroll
        for (int i = 0; i < 4; ++i)
            af[i]  = *(const bf16x8*)(&As[(wr * 64 + i * 16 + l16) * 32 + quad * 8]);
#pragma unroll
        for (int j = 0; j < NJ; ++j)
            bfv[j] = *(const bf16x8*)(&Bs[(wc * WN + j * 16 + l16) * 32 + quad * 8]);
#pragma unroll
        for (int i = 0; i < 4; ++i)
#pragma unroll
            for (int j = 0; j < NJ; ++j)
                acc[i][j] = __builtin_amdgcn_mfma_f32_16x16x32_bf16(af[i], bfv[j], acc[i][j], 0, 0, 0);
    }

    // epilogue
#pragma unroll
    for (int j = 0; j < NJ; ++j) {
        int n = n0 + wc * WN + j * 16 + l16;
        float bval;
        int which = 0, n2 = n;
        if constexpr (MODE == MODE_QKV) {
            which = n / D_;   // wave-uniform per j (16-span never crosses 768)
            n2 = n - which * D_;
            const void* bp = which == 0 ? b0 : (which == 1 ? b1 : b2);
            bval = dynld(bp, n2, f32in);
        } else {
            bval = dynld(b0, n, f32in);
        }
#pragma unroll
        for (int i = 0; i < 4; ++i) {
#pragma unroll
            for (int r = 0; r < 4; ++r) {
                int m = m0 + wr * 64 + i * 16 + quad * 4 + r;
                float v = acc[i][j][r] + bval;
                if constexpr (MODE == MODE_QKV) {
                    int b  = m >> 11;
                    int ss = m & (S_ - 1);
                    int h  = n2 / HD_;
                    int hd = n2 - h * HD_;
                    int bh = b * H_ + h;
                    if (which == 0) v *= QSCALE;   // fold softmax scale into Q
                    size_t dst;
                    if (which < 2)  // Q,K: [bh][S][HD]
                        dst = (size_t)which * (MSZ * D_) + ((size_t)bh * S_ + ss) * HD_ + hd;
                    else            // V transposed: [bh][HD][S]
                        dst = (size_t)2 * (MSZ * D_) + ((size_t)bh * HD_ + hd) * S_ + ss;
                    out[dst] = (bf16)v;
                } else if constexpr (MODE == MODE_RES) {
                    size_t ri = (size_t)m * N + n;
                    float rv = RESDYN ? dynld(res, ri, f32in) : (float)((const bf16*)res)[ri];
                    out[ri] = (bf16)(v + rv);
                } else {
                    out[(size_t)m * N + n] = (bf16)gelu_f(v);
                }
            }
        }
    }
}

// Flash attention, KV-tile 64, fixed-max softmax (p = 2^(sacc-M0), scale
// pre-folded into Q). Q,K: [bh][S][96]; Vt_g: [bh][96][S]. grid (S/64, B*H).
__global__ __launch_bounds__(256) void flash_kernel(
    const bf16* __restrict__ Q, const bf16* __restrict__ Kk,
    const bf16* __restrict__ Vt_g, bf16* __restrict__ ctx)
{
    __shared__ __align__(16) bf16 Ks[64][104];
    __shared__ __align__(16) bf16 Vs[96][72];
    __shared__ __align__(16) bf16 Ps[4][16][72];  // per-wave P [q][kv]

    const int tid  = threadIdx.x;
    const int w    = tid >> 6;
    const int lane = tid & 63;
    const int quad = lane >> 4;
    const int l16  = lane & 15;
    const int bh   = blockIdx.y;
    const size_t base = (size_t)bh * S_ * HD_;
    const int q0   = blockIdx.x * 64 + w * 16;

    bf16x8 qf[3];
#pragma unroll
    for (int ch = 0; ch < 3; ++ch)
        qf[ch] = *(const bf16x8*)(Q + base + (size_t)(q0 + l16) * HD_ + ch * 32 + quad * 8);

    f32x4 oacc[6];
#pragma unroll
    for (int c = 0; c < 6; ++c) oacc[c] = (f32x4){0.f, 0.f, 0.f, 0.f};
    float lsum[4] = {0.f, 0.f, 0.f, 0.f};

    for (int kv0 = 0; kv0 < S_; kv0 += 64) {
        __syncthreads();
#pragma unroll
        for (int jj = 0; jj < 3; ++jj) {
            int i  = tid + jj * 256;
            int r  = i / 12;
            int c8 = (i % 12) * 8;
            *(bf16x8*)(&Ks[r][c8]) =
                *(const bf16x8*)(Kk + base + (size_t)(kv0 + r) * HD_ + c8);
            int hd = i >> 3;
            int cb = (i & 7) * 8;
            *(bf16x8*)(&Vs[hd][cb]) =
                *(const bf16x8*)(Vt_g + base + (size_t)hd * S_ + kv0 + cb);
        }
        __syncthreads();

        // S = (Q*QSCALE) K^T : four 16x16 kv-tiles
        f32x4 sacc[4];
#pragma unroll
        for (int t = 0; t < 4; ++t) {
            sacc[t] = (f32x4){0.f, 0.f, 0.f, 0.f};
#pragma unroll
            for (int ch = 0; ch < 3; ++ch) {
                bf16x8 kf = *(const bf16x8*)(&Ks[t * 16 + l16][ch * 32 + quad * 8]);
                sacc[t] = __builtin_amdgcn_mfma_f32_16x16x32_bf16(qf[ch], kf, sacc[t], 0, 0, 0);
            }
        }

        // fixed-max softmax: p = 2^(sacc - M0); per-lane partial row sums only
#pragma unroll
        for (int r = 0; r < 4; ++r) {
            int qr = quad * 4 + r;
            float p0 = exp2f(sacc[0][r] - M0_);
            float p1 = exp2f(sacc[1][r] - M0_);
            float p2 = exp2f(sacc[2][r] - M0_);
            float p3 = exp2f(sacc[3][r] - M0_);
            lsum[r] += (p0 + p1) + (p2 + p3);
            Ps[w][qr][l16]      = (bf16)p0;
            Ps[w][qr][16 + l16] = (bf16)p1;
            Ps[w][qr][32 + l16] = (bf16)p2;
            Ps[w][qr][48 + l16] = (bf16)p3;
        }
        // no barrier: Ps is per-wave; in-wave ds ordering (lgkmcnt) suffices

        // O += P @ V   (two K=32 halves)
        bf16x8 pf0 = *(const bf16x8*)(&Ps[w][l16][quad * 8]);
        bf16x8 pf1 = *(const bf16x8*)(&Ps[w][l16][32 + quad * 8]);
#pragma unroll
        for (int c = 0; c < 6; ++c) {
            bf16x8 vf0 = *(const bf16x8*)(&Vs[c * 16 + l16][quad * 8]);
            bf16x8 vf1 = *(const bf16x8*)(&Vs[c * 16 + l16][32 + quad * 8]);
            oacc[c] = __builtin_amdgcn_mfma_f32_16x16x32_bf16(pf0, vf0, oacc[c], 0, 0, 0);
            oacc[c] = __builtin_amdgcn_mfma_f32_16x16x32_bf16(pf1, vf1, oacc[c], 0, 0, 0);
        }
    }

    // row sums: one shuffle tree at the end (row qr lives in the quad's 16 lanes)
#pragma unroll
    for (int r = 0; r < 4; ++r) {
#pragma unroll
        for (int off = 1; off < 16; off <<= 1) lsum[r] += __shfl_xor(lsum[r], off);
    }

    const int b = bh >> 3, h = bh & 7;
#pragma unroll
    for (int r = 0; r < 4; ++r) {
        float inv = 1.0f / lsum[r];
        int srow = q0 + quad * 4 + r;
        size_t rowbase = ((size_t)b * S_ + srow) * D_ + h * HD_;
#pragma unroll
        for (int c = 0; c < 6; ++c)
            ctx[rowbase + c * 16 + l16] = (bf16)(oacc[c][r] * inv);
    }
}

// LayerNorm over D=768: one wave per row (12 el/lane, bf16x4 vector I/O).
template<bool OUTDYN>
__global__ __launch_bounds__(256) void ln_kernel(
    const bf16* __restrict__ in, const void* __restrict__ g, const void* __restrict__ be,
    void* __restrict__ out, const void* __restrict__ sniffp)
{
    const bool f32in = sniff_f32(sniffp);
    const int w = threadIdx.x >> 6, lane = threadIdx.x & 63;
    const int row = blockIdx.x * 4 + w;
    const size_t rbase = (size_t)row * D_ + lane * 12;

    float v[12];
#pragma unroll
    for (int j = 0; j < 3; ++j) {
        bf16x4 t = *(const bf16x4*)(in + rbase + j * 4);
#pragma unroll
        for (int e = 0; e < 4; ++e) v[j * 4 + e] = (float)t[e];
    }
    float sum = 0.f;
#pragma unroll
    for (int j = 0; j < 12; ++j) sum += v[j];
#pragma unroll
    for (int off = 1; off < 64; off <<= 1) sum += __shfl_xor(sum, off);
    float mu = sum * (1.0f / D_);
    float sq = 0.f;
#pragma unroll
    for (int j = 0; j < 12; ++j) { v[j] -= mu; sq += v[j] * v[j]; }
#pragma unroll
    for (int off = 1; off < 64; off <<= 1) sq += __shfl_xor(sq, off);
    float rstd = rsqrtf(sq * (1.0f / D_) + 1e-5f);

    if (OUTDYN && f32in) {
        float* op = (float*)out + rbase;
#pragma unroll
        for (int j = 0; j < 3; ++j) {
            f32x4 t;
#pragma unroll
            for (int e = 0; e < 4; ++e) {
                int c = lane * 12 + j * 4 + e;
                t[e] = v[j * 4 + e] * rstd * dynld(g, c, true) + dynld(be, c, true);
            }
            *(f32x4*)(op + j * 4) = t;
        }
    } else {
        bf16* op = (bf16*)out + rbase;
#pragma unroll
        for (int j = 0; j < 3; ++j) {
            bf16x4 t;
#pragma unroll
            for (int e = 0; e < 4; ++e) {
                int c = lane * 12 + j * 4 + e;
                t[e] = (bf16)(v[j * 4 + e] * rstd * dynld(g, c, f32in) + dynld(be, c, f32in));
            }
            *(bf16x4*)(op + j * 4) = t;
        }
    }
}

// Transpose src [R][C] (dyn dtype) -> dst [C][R] bf16. 64x64 tiles.
__global__ __launch_bounds__(256) void transpose_kernel(
    const void* __restrict__ src, bf16* __restrict__ dst, int R, int C)
{
    __shared__ bf16 t[64][65];
    const bool f32in = sniff_f32(src);
    const int c0 = blockIdx.x * 64, r0 = blockIdx.y * 64;
    const int tx = threadIdx.x & 63, ty = threadIdx.x >> 6;
#pragma unroll
    for (int i = 0; i < 16; ++i) {
        int rr = ty + i * 4;
        t[rr][tx] = (bf16)dynld(src, (size_t)(r0 + rr) * C + c0 + tx, f32in);
    }
    __syncthreads();
#pragma unroll
    for (int i = 0; i < 16; ++i) {
        int cc = ty + i * 4;
        dst[(size_t)(c0 + cc) * R + r0 + tx] = t[tx][cc];
    }
}

extern "C" void kernel_launch(void* const* d_in, const int* in_sizes, int n_in,
                              void* d_out, int out_size, void* d_ws, size_t ws_size,
                              hipStream_t stream)
{
    (void)in_sizes; (void)n_in; (void)out_size;
    const void* x   = d_in[0];
    const void* Wq  = d_in[1];
    const void* bq  = d_in[2];
    const void* Wk  = d_in[3];
    const void* bk  = d_in[4];
    const void* Wv  = d_in[5];
    const void* bv  = d_in[6];
    const void* Wo  = d_in[7];
    const void* bo  = d_in[8];
    const void* g1  = d_in[9];
    const void* be1 = d_in[10];
    const void* W1  = d_in[11];
    const void* bf1 = d_in[12];
    const void* W2  = d_in[13];
    const void* bf2 = d_in[14];
    const void* g2  = d_in[15];
    const void* be2 = d_in[16];

    const size_t REG = (size_t)MSZ * D_ * 2;  // 12.58 MB
    char* p = (char*)d_ws;
    bf16* R0 = (bf16*)p;             // Q            -> x1
    bf16* R1 = (bf16*)(p + REG);     // K            -> WoT|W1T|W2T
    bf16* R2 = (bf16*)(p + 2 * REG); // V^T          -> h chunk (small path)
    bf16* R3 = (bf16*)(p + 3 * REG); // y1           -> y2
    bf16* R4 = (bf16*)(p + 4 * REG); // h full (big path only, 4 REG)
    const bool bigws = ws_size >= 8 * REG;

    bf16* qkvT = (bf16*)d_out;       // WqT|WkT|WvT (3.54 MB) before flash
    bf16* ctx  = (bf16*)d_out;       // after QKV GEMM

    dim3 blk(256);

    // 1) transpose Wq/Wk/Wv -> qkvT [2304][768]
    transpose_kernel<<<dim3(12, 12), blk, 0, stream>>>(Wq, qkvT, D_, D_);
    transpose_kernel<<<dim3(12, 12), blk, 0, stream>>>(Wk, qkvT + (size_t)D_ * D_, D_, D_);
    transpose_kernel<<<dim3(12, 12), blk, 0, stream>>>(Wv, qkvT + 2 * (size_t)D_ * D_, D_, D_);

    // 2) fused QKV GEMM: [8192 x 2304] -> Q*QSCALE(R0), K(R1), V^T(R2)
    gemm2_kernel<MODE_QKV, true, false, 128><<<dim3(MSZ / 128, 2304 / 128), blk, 0, stream>>>(
        x, qkvT, bq, bk, bv, nullptr, R0, MSZ, 2304, D_, Wq);

    // 3) flash attention -> ctx (d_out; qkvT dead)
    flash_kernel<<<dim3(S_ / 64, B_ * H_), blk, 0, stream>>>(R0, R1, R2, ctx);

    // 4) transpose Wo/W1/W2 into R1 (K dead)
    bf16* WoT = R1;
    bf16* W1T = WoT + (size_t)D_ * D_;
    bf16* W2T = W1T + (size_t)D_ * EXPD_;
    transpose_kernel<<<dim3(12, 12), blk, 0, stream>>>(Wo, WoT, D_, D_);
    transpose_kernel<<<dim3(48, 12), blk, 0, stream>>>(W1, W1T, D_, EXPD_);
    transpose_kernel<<<dim3(12, 48), blk, 0, stream>>>(W2, W2T, EXPD_, D_);

    // 5) y1 = ctx@Wo + bo + x -> R3   (BN=64: 768 blocks, 3/CU)
    gemm2_kernel<MODE_RES, false, true, 64><<<dim3(MSZ / 128, D_ / 64), blk, 0, stream>>>(
        ctx, WoT, bo, nullptr, nullptr, x, R3, MSZ, D_, D_, Wq);

    // 6) x1 = LN1(y1) -> R0 (Q dead)
    bf16* x1b = R0;
    ln_kernel<false><<<dim3(MSZ / 4), blk, 0, stream>>>(R3, g1, be1, x1b, Wq);

    // 7/8) FFN (y2 -> R3; y1 dead)
    if (bigws) {
        gemm2_kernel<MODE_GELU, false, false, 128><<<dim3(MSZ / 128, EXPD_ / 128), blk, 0, stream>>>(
            x1b, W1T, bf1, nullptr, nullptr, nullptr, R4, MSZ, EXPD_, D_, Wq);
        gemm2_kernel<MODE_RES, false, false, 64><<<dim3(MSZ / 128, D_ / 64), blk, 0, stream>>>(
            R4, W2T, bf2, nullptr, nullptr, x1b, R3, MSZ, D_, EXPD_, Wq);
    } else {
        const int CH = 2048;  // h chunk = 12.58 MB -> R2 (V dead)
        for (int c0 = 0; c0 < MSZ; c0 += CH) {
            const bf16* x1c = x1b + (size_t)c0 * D_;
            gemm2_kernel<MODE_GELU, false, false, 128><<<dim3(CH / 128, EXPD_ / 128), blk, 0, stream>>>(
                x1c, W1T, bf1, nullptr, nullptr, nullptr, R2, CH, EXPD_, D_, Wq);
            gemm2_kernel<MODE_RES, false, false, 64><<<dim3(CH / 128, D_ / 64), blk, 0, stream>>>(
                R2, W2T, bf2, nullptr, nullptr, x1c, R3 + (size_t)c0 * D_, CH, D_, EXPD_, Wq);
        }
    }

    // 9) out = LN2(y2) -> d_out (ctx dead)
    ln_kernel<true><<<dim3(MSZ / 4), blk, 0, stream>>>(R3, g2, be2, d_out, Wq);
}

// Round 6
// 494.881 us; speedup vs baseline: 2.4135x; 1.1293x over previous
//
#include <hip/hip_runtime.h>
#include <hip/hip_bf16.h>
#include <math.h>
#include <stdint.h>

// ---- problem constants ----
#define B_    4
#define S_    2048
#define D_    768
#define H_    8
#define HD_   96
#define EXPD_ 3072
#define MSZ   8192   // B*S

#define QSCALE 0.14724439f   // HD^-0.5 * log2(e), folded into Q at QKV epilogue
#define M0_    12.0f         // fixed softmax exponent offset

typedef __bf16 bf16;
typedef __bf16 bf16x4 __attribute__((ext_vector_type(4)));
typedef __bf16 bf16x8 __attribute__((ext_vector_type(8)));
typedef float  f32x4  __attribute__((ext_vector_type(4)));

typedef __attribute__((address_space(1))) const uint32_t gu32;
typedef __attribute__((address_space(3))) uint32_t lu32;

__device__ __forceinline__ void async_copy16(const void* g, void* l) {
    __builtin_amdgcn_global_load_lds((gu32*)g, (lu32*)l, 16, 0, 0);
}

__device__ __forceinline__ float gelu_f(float x) {
    float x3 = x * x * x;
    return 0.5f * x * (1.0f + tanhf(0.7978845608028654f * (x + 0.044715f * x3)));
}

// Runtime dtype sniff: f32 buffer read as bf16 at even indices yields random
// exponents -> some |v|>=1e3 among 64 samples w.p. ~1. bf16 weights never trip.
__device__ __forceinline__ bool sniff_f32(const void* p) {
    const bf16* pb = (const bf16*)p;
    float v = (float)pb[2 * (threadIdx.x & 63)];
    bool big = !(fabsf(v) < 1000.0f);
    return __any(big) != 0;
}

__device__ __forceinline__ float dynld(const void* p, size_t i, bool f32in) {
    return f32in ? ((const float*)p)[i] : (float)((const bf16*)p)[i];
}

// Cast src (sniffed f32/bf16) -> bf16, 8 el/thread.
__global__ __launch_bounds__(256) void cast_kernel(
    const void* __restrict__ src, bf16* __restrict__ dst)
{
    const bool f32in = sniff_f32(src);
    size_t i = ((size_t)blockIdx.x * 256 + threadIdx.x) * 8;
    if (f32in) {
        f32x4 a = *(const f32x4*)((const float*)src + i);
        f32x4 b = *(const f32x4*)((const float*)src + i + 4);
        bf16x8 r;
#pragma unroll
        for (int e = 0; e < 4; ++e) { r[e] = (bf16)a[e]; r[e + 4] = (bf16)b[e]; }
        *(bf16x8*)(dst + i) = r;
    } else {
        *(bf16x8*)(dst + i) = *(const bf16x8*)((const bf16*)src + i);
    }
}

#define MODE_QKV  0   // fused QKV: Q(*QSCALE),K -> [bh][S][HD]; V -> [bh][HD][S]
#define MODE_RES  1   // out bf16 = c + bias + res
#define MODE_GELU 2   // out bf16 = gelu(c + bias)

// m97-style GEMM: C = A(MxK) @ Bt(NxK)^T + bias. Tile 128xBN, BK=32, 4 waves,
// global_load_lds width-16 staging, stride-32 LDS.
template<int MODE, bool ADYN, bool RESDYN, int BN>
__global__ __launch_bounds__(256) void gemm2_kernel(
    const void* __restrict__ A, const bf16* __restrict__ Bt,
    const void* __restrict__ b0, const void* __restrict__ b1, const void* __restrict__ b2,
    const void* __restrict__ res, bf16* __restrict__ out,
    int M, int N, int K, const void* __restrict__ sniffp)
{
    constexpr int WN = BN / 2;
    constexpr int NJ = WN / 16;
    __shared__ __align__(16) bf16 As[128 * 32];
    __shared__ __align__(16) bf16 Bs[BN * 32];

    const bool f32in = sniff_f32(sniffp);
    const int tid  = threadIdx.x;
    const int w    = tid >> 6;
    const int lane = tid & 63;
    const int quad = lane >> 4;
    const int l16  = lane & 15;
    const int wr   = w >> 1, wc = w & 1;
    const int m0   = blockIdx.x * 128;
    const int n0   = blockIdx.y * BN;

    const int rsub = lane >> 2;
    const int cb8  = (lane & 3) * 8;

    f32x4 acc[4][NJ];
#pragma unroll
    for (int i = 0; i < 4; ++i)
#pragma unroll
        for (int j = 0; j < NJ; ++j) acc[i][j] = (f32x4){0.f, 0.f, 0.f, 0.f};

    const bf16*  Abf = (const bf16*)A;
    const float* Af  = (const float*)A;

    for (int k0 = 0; k0 < K; k0 += 32) {
        __syncthreads();
        if (ADYN && f32in) {
#pragma unroll
            for (int a = 0; a < 2; ++a) {
                int row = w * 32 + a * 16 + rsub;
                const float* sp = Af + (size_t)(m0 + row) * K + k0 + cb8;
                f32x4 u0 = *(const f32x4*)sp;
                f32x4 u1 = *(const f32x4*)(sp + 4);
                bf16x8 v;
#pragma unroll
                for (int e = 0; e < 4; ++e) { v[e] = (bf16)u0[e]; v[e + 4] = (bf16)u1[e]; }
                *(bf16x8*)(&As[(size_t)(w * 32 + a * 16) * 32 + lane * 8]) = v;
            }
        } else {
#pragma unroll
            for (int a = 0; a < 2; ++a) {
                int row = w * 32 + a * 16 + rsub;
                async_copy16(Abf + (size_t)(m0 + row) * K + k0 + cb8,
                             &As[(w * 32 + a * 16) * 32]);
            }
        }
#pragma unroll
        for (int a = 0; a < BN / 64; ++a) {
            int row = w * (BN / 4) + a * 16 + rsub;
            async_copy16(Bt + (size_t)(n0 + row) * K + k0 + cb8,
                         &Bs[(w * (BN / 4) + a * 16) * 32]);
        }
        __syncthreads();

        bf16x8 af[4], bfv[NJ];
#pragma unroll
        for (int i = 0; i < 4; ++i)
            af[i]  = *(const bf16x8*)(&As[(wr * 64 + i * 16 + l16) * 32 + quad * 8]);
#pragma unroll
        for (int j = 0; j < NJ; ++j)
            bfv[j] = *(const bf16x8*)(&Bs[(wc * WN + j * 16 + l16) * 32 + quad * 8]);
#pragma unroll
        for (int i = 0; i < 4; ++i)
#pragma unroll
            for (int j = 0; j < NJ; ++j)
                acc[i][j] = __builtin_amdgcn_mfma_f32_16x16x32_bf16(af[i], bfv[j], acc[i][j], 0, 0, 0);
    }

#pragma unroll
    for (int j = 0; j < NJ; ++j) {
        int n = n0 + wc * WN + j * 16 + l16;
        float bval;
        int which = 0, n2 = n;
        if constexpr (MODE == MODE_QKV) {
            which = n / D_;   // wave-uniform per j
            n2 = n - which * D_;
            const void* bp = which == 0 ? b0 : (which == 1 ? b1 : b2);
            bval = dynld(bp, n2, f32in);
        } else {
            bval = dynld(b0, n, f32in);
        }
#pragma unroll
        for (int i = 0; i < 4; ++i) {
#pragma unroll
            for (int r = 0; r < 4; ++r) {
                int m = m0 + wr * 64 + i * 16 + quad * 4 + r;
                float v = acc[i][j][r] + bval;
                if constexpr (MODE == MODE_QKV) {
                    int b  = m >> 11;
                    int ss = m & (S_ - 1);
                    int h  = n2 / HD_;
                    int hd = n2 - h * HD_;
                    int bh = b * H_ + h;
                    if (which == 0) v *= QSCALE;
                    size_t dst;
                    if (which < 2)
                        dst = (size_t)which * (MSZ * D_) + ((size_t)bh * S_ + ss) * HD_ + hd;
                    else
                        dst = (size_t)2 * (MSZ * D_) + ((size_t)bh * HD_ + hd) * S_ + ss;
                    out[dst] = (bf16)v;
                } else if constexpr (MODE == MODE_RES) {
                    size_t ri = (size_t)m * N + n;
                    float rv = RESDYN ? dynld(res, ri, f32in) : (float)((const bf16*)res)[ri];
                    out[ri] = (bf16)(v + rv);
                } else {
                    out[(size_t)m * N + n] = (bf16)gelu_f(v);
                }
            }
        }
    }
}

// Flash attention, Q-tile 128 (wave owns 32 q rows = 2 m-tiles), KV-tile 64,
// fixed-max softmax. Q,K: [bh][S][96]; Vt_g: [bh][96][S]. grid (S/128, B*H).
__global__ __launch_bounds__(256) void flash_kernel(
    const bf16* __restrict__ Q, const bf16* __restrict__ Kk,
    const bf16* __restrict__ Vt_g, bf16* __restrict__ ctx)
{
    __shared__ __align__(16) bf16 Ks[64][104];
    __shared__ __align__(16) bf16 Vs[96][72];
    __shared__ __align__(16) bf16 Ps[4][32][72];  // per-wave P [q][kv]

    const int tid  = threadIdx.x;
    const int w    = tid >> 6;
    const int lane = tid & 63;
    const int quad = lane >> 4;
    const int l16  = lane & 15;
    const int bh   = blockIdx.y;
    const size_t base = (size_t)bh * S_ * HD_;
    const int q0   = blockIdx.x * 128 + w * 32;

    bf16x8 qf[2][3];
#pragma unroll
    for (int m = 0; m < 2; ++m)
#pragma unroll
        for (int ch = 0; ch < 3; ++ch)
            qf[m][ch] = *(const bf16x8*)(Q + base + (size_t)(q0 + m * 16 + l16) * HD_ + ch * 32 + quad * 8);

    f32x4 oacc[2][6];
#pragma unroll
    for (int m = 0; m < 2; ++m)
#pragma unroll
        for (int c = 0; c < 6; ++c) oacc[m][c] = (f32x4){0.f, 0.f, 0.f, 0.f};
    float lsum[2][4] = {{0.f, 0.f, 0.f, 0.f}, {0.f, 0.f, 0.f, 0.f}};

    for (int kv0 = 0; kv0 < S_; kv0 += 64) {
        __syncthreads();
#pragma unroll
        for (int jj = 0; jj < 3; ++jj) {
            int i  = tid + jj * 256;
            int r  = i / 12;
            int c8 = (i % 12) * 8;
            *(bf16x8*)(&Ks[r][c8]) =
                *(const bf16x8*)(Kk + base + (size_t)(kv0 + r) * HD_ + c8);
            int hd = i >> 3;
            int cb = (i & 7) * 8;
            *(bf16x8*)(&Vs[hd][cb]) =
                *(const bf16x8*)(Vt_g + base + (size_t)hd * S_ + kv0 + cb);
        }
        __syncthreads();

        // S = (Q*QSCALE) K^T and softmax, per m-tile
#pragma unroll
        for (int m = 0; m < 2; ++m) {
            f32x4 sacc[4];
#pragma unroll
            for (int t = 0; t < 4; ++t) {
                sacc[t] = (f32x4){0.f, 0.f, 0.f, 0.f};
#pragma unroll
                for (int ch = 0; ch < 3; ++ch) {
                    bf16x8 kf = *(const bf16x8*)(&Ks[t * 16 + l16][ch * 32 + quad * 8]);
                    sacc[t] = __builtin_amdgcn_mfma_f32_16x16x32_bf16(qf[m][ch], kf, sacc[t], 0, 0, 0);
                }
            }
#pragma unroll
            for (int r = 0; r < 4; ++r) {
                int qr = m * 16 + quad * 4 + r;
                float p0 = exp2f(sacc[0][r] - M0_);
                float p1 = exp2f(sacc[1][r] - M0_);
                float p2 = exp2f(sacc[2][r] - M0_);
                float p3 = exp2f(sacc[3][r] - M0_);
                lsum[m][r] += (p0 + p1) + (p2 + p3);
                Ps[w][qr][l16]      = (bf16)p0;
                Ps[w][qr][16 + l16] = (bf16)p1;
                Ps[w][qr][32 + l16] = (bf16)p2;
                Ps[w][qr][48 + l16] = (bf16)p3;
            }
        }
        // no barrier: Ps is per-wave (in-wave lgkmcnt ordering suffices)

        bf16x8 pf[2][2];
#pragma unroll
        for (int m = 0; m < 2; ++m) {
            pf[m][0] = *(const bf16x8*)(&Ps[w][m * 16 + l16][quad * 8]);
            pf[m][1] = *(const bf16x8*)(&Ps[w][m * 16 + l16][32 + quad * 8]);
        }
#pragma unroll
        for (int c = 0; c < 6; ++c) {
            bf16x8 vf0 = *(const bf16x8*)(&Vs[c * 16 + l16][quad * 8]);
            bf16x8 vf1 = *(const bf16x8*)(&Vs[c * 16 + l16][32 + quad * 8]);
#pragma unroll
            for (int m = 0; m < 2; ++m) {
                oacc[m][c] = __builtin_amdgcn_mfma_f32_16x16x32_bf16(pf[m][0], vf0, oacc[m][c], 0, 0, 0);
                oacc[m][c] = __builtin_amdgcn_mfma_f32_16x16x32_bf16(pf[m][1], vf1, oacc[m][c], 0, 0, 0);
            }
        }
    }

#pragma unroll
    for (int m = 0; m < 2; ++m)
#pragma unroll
        for (int r = 0; r < 4; ++r)
#pragma unroll
            for (int off = 1; off < 16; off <<= 1)
                lsum[m][r] += __shfl_xor(lsum[m][r], off);

    const int b = bh >> 3, h = bh & 7;
#pragma unroll
    for (int m = 0; m < 2; ++m)
#pragma unroll
        for (int r = 0; r < 4; ++r) {
            float inv = 1.0f / lsum[m][r];
            int srow = q0 + m * 16 + quad * 4 + r;
            size_t rowbase = ((size_t)b * S_ + srow) * D_ + h * HD_;
#pragma unroll
            for (int c = 0; c < 6; ++c)
                ctx[rowbase + c * 16 + l16] = (bf16)(oacc[m][c][r] * inv);
        }
}

// LayerNorm over D=768: one wave per row (12 el/lane, bf16x4 vector I/O).
template<bool OUTDYN>
__global__ __launch_bounds__(256) void ln_kernel(
    const bf16* __restrict__ in, const void* __restrict__ g, const void* __restrict__ be,
    void* __restrict__ out, const void* __restrict__ sniffp)
{
    const bool f32in = sniff_f32(sniffp);
    const int w = threadIdx.x >> 6, lane = threadIdx.x & 63;
    const int row = blockIdx.x * 4 + w;
    const size_t rbase = (size_t)row * D_ + lane * 12;

    float v[12];
#pragma unroll
    for (int j = 0; j < 3; ++j) {
        bf16x4 t = *(const bf16x4*)(in + rbase + j * 4);
#pragma unroll
        for (int e = 0; e < 4; ++e) v[j * 4 + e] = (float)t[e];
    }
    float sum = 0.f;
#pragma unroll
    for (int j = 0; j < 12; ++j) sum += v[j];
#pragma unroll
    for (int off = 1; off < 64; off <<= 1) sum += __shfl_xor(sum, off);
    float mu = sum * (1.0f / D_);
    float sq = 0.f;
#pragma unroll
    for (int j = 0; j < 12; ++j) { v[j] -= mu; sq += v[j] * v[j]; }
#pragma unroll
    for (int off = 1; off < 64; off <<= 1) sq += __shfl_xor(sq, off);
    float rstd = rsqrtf(sq * (1.0f / D_) + 1e-5f);

    if (OUTDYN && f32in) {
        float* op = (float*)out + rbase;
#pragma unroll
        for (int j = 0; j < 3; ++j) {
            f32x4 t;
#pragma unroll
            for (int e = 0; e < 4; ++e) {
                int c = lane * 12 + j * 4 + e;
                t[e] = v[j * 4 + e] * rstd * dynld(g, c, true) + dynld(be, c, true);
            }
            *(f32x4*)(op + j * 4) = t;
        }
    } else {
        bf16* op = (bf16*)out + rbase;
#pragma unroll
        for (int j = 0; j < 3; ++j) {
            bf16x4 t;
#pragma unroll
            for (int e = 0; e < 4; ++e) {
                int c = lane * 12 + j * 4 + e;
                t[e] = (bf16)(v[j * 4 + e] * rstd * dynld(g, c, f32in) + dynld(be, c, f32in));
            }
            *(bf16x4*)(op + j * 4) = t;
        }
    }
}

// Transpose 64x64 tile helper
__device__ __forceinline__ void transpose_tile(
    const void* __restrict__ src, bf16* __restrict__ dst, int R, int C,
    int r0, int c0, bool f32in)
{
    __shared__ bf16 t[64][65];
    const int tx = threadIdx.x & 63, ty = threadIdx.x >> 6;
#pragma unroll
    for (int i = 0; i < 16; ++i) {
        int rr = ty + i * 4;
        t[rr][tx] = (bf16)dynld(src, (size_t)(r0 + rr) * C + c0 + tx, f32in);
    }
    __syncthreads();
#pragma unroll
    for (int i = 0; i < 16; ++i) {
        int cc = ty + i * 4;
        dst[(size_t)(c0 + cc) * R + r0 + tx] = t[tx][cc];
    }
}

// Wq/Wk/Wv (all 768x768) -> dst + z*D*D, one launch, grid (12,12,3)
__global__ __launch_bounds__(256) void transpose_qkv_kernel(
    const void* __restrict__ s0, const void* __restrict__ s1, const void* __restrict__ s2,
    bf16* __restrict__ dst)
{
    const void* src = blockIdx.z == 0 ? s0 : (blockIdx.z == 1 ? s1 : s2);
    const bool f32in = sniff_f32(src);
    transpose_tile(src, dst + (size_t)blockIdx.z * D_ * D_, D_, D_,
                   blockIdx.y * 64, blockIdx.x * 64, f32in);
}

// Wo(768x768)/W1(768x3072)/W2(3072x768) -> WoT|W1T|W2T, grid (48,48,3) w/ guards
__global__ __launch_bounds__(256) void transpose_mlp_kernel(
    const void* __restrict__ s0, const void* __restrict__ s1, const void* __restrict__ s2,
    bf16* __restrict__ dst)
{
    int z = blockIdx.z;
    const void* src = z == 0 ? s0 : (z == 1 ? s1 : s2);
    int R = z == 2 ? EXPD_ : D_;
    int C = z == 1 ? EXPD_ : D_;
    size_t off = z == 0 ? 0 : (z == 1 ? (size_t)D_ * D_ : (size_t)D_ * D_ + (size_t)D_ * EXPD_);
    int r0 = blockIdx.y * 64, c0 = blockIdx.x * 64;
    if (r0 >= R || c0 >= C) return;
    const bool f32in = sniff_f32(src);
    transpose_tile(src, dst + off, R, C, r0, c0, f32in);
}

extern "C" void kernel_launch(void* const* d_in, const int* in_sizes, int n_in,
                              void* d_out, int out_size, void* d_ws, size_t ws_size,
                              hipStream_t stream)
{
    (void)in_sizes; (void)n_in; (void)out_size;
    const void* x   = d_in[0];
    const void* Wq  = d_in[1];
    const void* bq  = d_in[2];
    const void* Wk  = d_in[3];
    const void* bk  = d_in[4];
    const void* Wv  = d_in[5];
    const void* bv  = d_in[6];
    const void* Wo  = d_in[7];
    const void* bo  = d_in[8];
    const void* g1  = d_in[9];
    const void* be1 = d_in[10];
    const void* W1  = d_in[11];
    const void* bf1 = d_in[12];
    const void* W2  = d_in[13];
    const void* bf2 = d_in[14];
    const void* g2  = d_in[15];
    const void* be2 = d_in[16];

    const size_t REG = (size_t)MSZ * D_ * 2;  // 12.58 MB
    char* p = (char*)d_ws;
    bf16* R0 = (bf16*)p;             // Q            -> x1
    bf16* R1 = (bf16*)(p + REG);     // K            -> WoT|W1T|W2T
    bf16* R2 = (bf16*)(p + 2 * REG); // V^T          -> h chunk (tier<=1)
    bf16* R3 = (bf16*)(p + 3 * REG); // y1           -> y2
    bf16* ctx = (bf16*)d_out;        // also qkvT home before flash

    // tiers: 0 = 4 REG (no cast, CH2048) | 1 = 5 REG (+xb, CH2048)
    //        2 = 7 REG (+xb, CH4096)     | 3 = 9 REG (+xb, full FFN)
    int tier = 0;
    if      (ws_size >= 9 * REG) tier = 3;
    else if (ws_size >= 7 * REG) tier = 2;
    else if (ws_size >= 5 * REG) tier = 1;
    bf16* xb = (bf16*)(p + (tier == 3 ? 8 : 4) * REG);
    bf16* hb = tier == 3 ? (bf16*)(p + 4 * REG)
             : tier == 2 ? (bf16*)(p + 5 * REG) : R2;
    const int CH = tier == 3 ? MSZ : (tier == 2 ? 4096 : 2048);

    bf16* qkvT = (bf16*)d_out;       // WqT|WkT|WvT (3.54 MB) before flash
    dim3 blk(256);

    // 0) cast x -> bf16 (tier >= 1)
    if (tier >= 1) cast_kernel<<<dim3(MSZ * D_ / (256 * 8)), blk, 0, stream>>>(x, xb);

    // 1) transpose Wq/Wk/Wv -> qkvT [2304][768] (one launch)
    transpose_qkv_kernel<<<dim3(12, 12, 3), blk, 0, stream>>>(Wq, Wk, Wv, qkvT);

    // 2) fused QKV GEMM -> Q*QSCALE(R0), K(R1), V^T(R2)
    if (tier >= 1)
        gemm2_kernel<MODE_QKV, false, false, 128><<<dim3(MSZ / 128, 2304 / 128), blk, 0, stream>>>(
            xb, qkvT, bq, bk, bv, nullptr, R0, MSZ, 2304, D_, Wq);
    else
        gemm2_kernel<MODE_QKV, true, false, 128><<<dim3(MSZ / 128, 2304 / 128), blk, 0, stream>>>(
            x, qkvT, bq, bk, bv, nullptr, R0, MSZ, 2304, D_, Wq);

    // 3) flash attention -> ctx (d_out; qkvT dead)
    flash_kernel<<<dim3(S_ / 128, B_ * H_), blk, 0, stream>>>(R0, R1, R2, ctx);

    // 4) transpose Wo/W1/W2 into R1 (K dead)
    bf16* WoT = R1;
    bf16* W1T = WoT + (size_t)D_ * D_;
    bf16* W2T = W1T + (size_t)D_ * EXPD_;
    transpose_mlp_kernel<<<dim3(48, 48, 3), blk, 0, stream>>>(Wo, W1, W2, WoT);

    // 5) y1 = ctx@Wo + bo + x -> R3
    if (tier >= 1)
        gemm2_kernel<MODE_RES, false, false, 64><<<dim3(MSZ / 128, D_ / 64), blk, 0, stream>>>(
            ctx, WoT, bo, nullptr, nullptr, xb, R3, MSZ, D_, D_, Wq);
    else
        gemm2_kernel<MODE_RES, false, true, 64><<<dim3(MSZ / 128, D_ / 64), blk, 0, stream>>>(
            ctx, WoT, bo, nullptr, nullptr, x, R3, MSZ, D_, D_, Wq);

    // 6) x1 = LN1(y1) -> R0 (Q dead)
    bf16* x1b = R0;
    ln_kernel<false><<<dim3(MSZ / 4), blk, 0, stream>>>(R3, g1, be1, x1b, Wq);

    // 7/8) FFN chunked over M (y2 -> R3)
    for (int c0 = 0; c0 < MSZ; c0 += CH) {
        const bf16* x1c = x1b + (size_t)c0 * D_;
        gemm2_kernel<MODE_GELU, false, false, 128><<<dim3(CH / 128, EXPD_ / 128), blk, 0, stream>>>(
            x1c, W1T, bf1, nullptr, nullptr, nullptr, hb, CH, EXPD_, D_, Wq);
        gemm2_kernel<MODE_RES, false, false, 64><<<dim3(CH / 128, D_ / 64), blk, 0, stream>>>(
            hb, W2T, bf2, nullptr, nullptr, x1c, R3 + (size_t)c0 * D_, CH, D_, EXPD_, Wq);
    }

    // 9) out = LN2(y2) -> d_out (ctx dead)
    ln_kernel<true><<<dim3(MSZ / 4), blk, 0, stream>>>(R3, g2, be2, d_out, Wq);
}